// Round 2
// baseline (1830.123 us; speedup 1.0000x reference)
//
#include <hip/hip_runtime.h>
#include <math.h>

// ---------------- problem constants ----------------
#define BATCH 16
#define RWS   128     // rows
#define TT    128     // time steps per row (cols*C)
#define HH    32      // hidden
#define GG    96      // 3*H gate rows
#define RPB   8       // rows per block (diagonal pipeline inside block)
#define NRG   (RWS/RPB) // 16 row groups -> chain of 16 blocks, 15 flag hops
#define WSTR  34      // padded LDS row stride (floats) for [96x32] mats -> 2-way (free) b64 banks
#define FSTR  16      // flag stride in ints (64 B) to avoid coherence-line ping-pong

// ---------------- workspace layout (bytes) ----------------
#define H2_BYTES   (BATCH*RWS*TT*HH*4)          // 33,554,432
#define FLAG_OFF   H2_BYTES
#define FLAG_BYTES (NRG*BATCH*FSTR*4)           // 16,384
#define PTAB_OFF   (FLAG_OFF + FLAG_BYTES)
#define WF_OFF     (PTAB_OFF + 258*GG*4)        // Ptab: 258*96 fp32

__device__ __forceinline__ float sigm(float x) { return 1.0f / (1.0f + __expf(-x)); }
__device__ __forceinline__ float tanhfast(float x) {
  x = fminf(fmaxf(x, -15.0f), 15.0f);
  float e = __expf(2.0f * x);
  return (e - 1.0f) / (e + 1.0f);
}

// dot over 32 elems; w from stride-34 LDS row (8B aligned), v is 32-elem LDS vector (broadcast)
__device__ __forceinline__ float dot32(const float* __restrict__ w, const float* __restrict__ v) {
  float a0 = 0.f, a1 = 0.f;
#pragma unroll
  for (int k = 0; k < HH; k += 4) {
    float2 w0 = *(const float2*)(w + k);
    float2 w1 = *(const float2*)(w + k + 2);
    float2 v0 = *(const float2*)(v + k);
    float2 v1 = *(const float2*)(v + k + 2);
    a0 = fmaf(w0.x, v0.x, fmaf(w0.y, v0.y, a0));
    a1 = fmaf(w1.x, v1.x, fmaf(w1.y, v1.y, a1));
  }
  return a0 + a1;
}

// ------------------------------------------------------------------
// prep: P[v][g] = b_ih0[g] + sum_k<64 Wih0[g][k] emb[v][k] + sum_k<65 Wih0[g][k] b_h2e[k]
//       Wf[g][j] = sum_k<65 Wih0[g][k] Wh2e[k][j]
// ------------------------------------------------------------------
__global__ __launch_bounds__(128)
void prep_kernel(const float* __restrict__ emb, const float* __restrict__ wih0,
                 const float* __restrict__ bih0, const float* __restrict__ wh2e,
                 const float* __restrict__ bh2e, float* __restrict__ Ptab,
                 float* __restrict__ Wfo) {
  const int blk = blockIdx.x, tid = threadIdx.x;
  if (blk < 258) {
    if (tid < GG) {
      const float* wr = wih0 + tid * 65;
      const float* e  = emb + blk * 64;
      float acc = bih0[tid];
      for (int k = 0; k < 64; ++k) acc = fmaf(wr[k], e[k], acc);
      for (int k = 0; k < 65; ++k) acc = fmaf(wr[k], bh2e[k], acc);
      Ptab[blk * GG + tid] = acc;
    }
  } else {
    const int g = blk - 258;
    if (tid < HH) {
      const float* wr = wih0 + g * 65;
      float acc = 0.f;
      for (int k = 0; k < 65; ++k) acc = fmaf(wr[k], wh2e[k * HH + tid], acc);
      Wfo[g * HH + tid] = acc;
    }
  }
}

// ------------------------------------------------------------------
// RNN wavefront kernel, v2: 8 rows per block pipelined diagonally.
// 256 blocks = (row-group 0..15) x (batch 0..15); 256 thr = (row s 0..7, j 0..31).
// Iteration i computes row s at t = i - s. Row->row handoff INSIDE the block
// goes through double-buffered LDS (h2a/h2b); only the group boundary (15 hops
// instead of 127) uses the agent-scope flag protocol.
// ONE __syncthreads per iteration: all per-layer LDS traffic is within a
// half-wave (a row = 32 consecutive tids, in-wave lgkmcnt ordering); the only
// cross-wave LDS traffic (h2 row s-1 -> s) is made race-free by the double
// buffer + the single barrier. Flag publish needs no second barrier: the
// bottom row (s=7) lives entirely in wave 3, so a wave-3 lane drains its own
// wave's agent stores with s_waitcnt vmcnt(0) and then publishes.
// ------------------------------------------------------------------
__device__ __forceinline__ void loadmat(const float* __restrict__ src, float* __restrict__ dst, int tid) {
  for (int i = tid; i < GG * HH; i += 256) dst[(i >> 5) * WSTR + (i & 31)] = src[i];
}

__global__ __launch_bounds__(256)
void rnn_kernel(const int* __restrict__ xg, const float* __restrict__ wih0,
                const float* __restrict__ whh0g, const float* __restrict__ bhh0g,
                const float* __restrict__ wih1g, const float* __restrict__ whh1g,
                const float* __restrict__ bih1g, const float* __restrict__ bhh1g,
                const float* __restrict__ wih2g, const float* __restrict__ whh2g,
                const float* __restrict__ bih2g, const float* __restrict__ bhh2g,
                const float* __restrict__ Ptab, const float* __restrict__ Wfg,
                float* __restrict__ h2buf, int* __restrict__ flags) {
  extern __shared__ float lds[];
  float* Wf    = lds;                 // 96*34
  float* Whh0  = Wf   + GG * WSTR;
  float* Wih1  = Whh0 + GG * WSTR;
  float* Whh1  = Wih1 + GG * WSTR;
  float* Wih2  = Whh1 + GG * WSTR;
  float* Whh2  = Wih2 + GG * WSTR;
  float* bias  = Whh2 + GG * WSTR;    // [bhh0|bih1|bhh1|bih2|bhh2] 5*96
  float* prevs = bias + 5 * GG;       // 32: global pv staging for s==0 row
  float* h0s   = prevs + HH;          // 8*32
  float* h1s   = h0s + RPB * HH;      // 8*32
  float* h2a   = h1s + RPB * HH;      // 8*32 double buffer A
  float* h2b   = h2a + RPB * HH;      // 8*32 double buffer B

  const int tid = threadIdx.x;
  const int j   = tid & 31;
  const int s   = tid >> 5;           // row within group
  const int g   = blockIdx.x >> 4;    // row group (chain position)
  const int bat = blockIdx.x & 15;    // batch
  const int row = g * RPB + s;

  loadmat(Wfg,   Wf,   tid);
  loadmat(whh0g, Whh0, tid);
  loadmat(wih1g, Wih1, tid);
  loadmat(whh1g, Whh1, tid);
  loadmat(wih2g, Wih2, tid);
  loadmat(whh2g, Whh2, tid);
  for (int i = tid; i < GG; i += 256) {
    bias[i]          = bhh0g[i];
    bias[GG + i]     = bih1g[i];
    bias[2 * GG + i] = bhh1g[i];
    bias[3 * GG + i] = bih2g[i];
    bias[4 * GG + i] = bhh2g[i];
  }
  h0s[tid] = 0.f; h1s[tid] = 0.f; h2a[tid] = 0.f; h2b[tid] = 0.f;
  if (tid < HH) prevs[tid] = 0.f;

  // row-position feature contribution, per-thread (rows differ within block)
  const float rowpos = (float)row * (2.0f / 128.0f) - 1.0f;
  const float rpr = wih0[j * 65 + 64] * rowpos;
  const float rpz = wih0[(32 + j) * 65 + 64] * rowpos;
  const float rpn = wih0[(64 + j) * 65 + 64] * rowpos;
  __syncthreads();

  float h0r = 0.f, h1r = 0.f, h2r = 0.f;
  const size_t xbase = (size_t)(bat * RWS + row) * TT;
  const size_t obase = (size_t)(bat * RWS + row) * TT * HH + j;
  const size_t pbase = (row > 0) ? ((size_t)(bat * RWS + (row - 1)) * TT * HH + j) : 0;
  int* myflag = flags + (g * BATCH + bat) * FSTR;
  const int* pflag = flags + ((g > 0 ? g - 1 : 0) * BATCH + bat) * FSTR;
  const float* hb0 = h0s + s * HH;
  const float* hb1 = h1s + s * HH;

  int vcur = xg[xbase];

  for (int i = 0; i < TT + RPB - 1; ++i) {
    const int t = i - s;                       // own time step
    const bool act = (t >= 0) && (t < TT);
    const float* h2rd = (i & 1) ? h2a : h2b;   // written at iter i-1 (init 0)
    float*       h2w  = (i & 1) ? h2b : h2a;   // written this iter

    // prefetch next token + P-table rows for current t (independent of flag wait)
    const int tn = t + 1;
    const int vnext = (tn >= 0 && tn < TT) ? xg[xbase + tn] : 0;
    const float Pr = Ptab[vcur * GG + j];
    const float Pz = Ptab[vcur * GG + 32 + j];
    const float Pn = Ptab[vcur * GG + 64 + j];

    // chain handoff: wait until producer group's bottom row finished t = i
    if (g > 0 && i < TT) {
      if (tid == 0) {
        const int want = i + 1;
        while (__hip_atomic_load(pflag, __ATOMIC_RELAXED, __HIP_MEMORY_SCOPE_AGENT) < want)
          __builtin_amdgcn_s_sleep(1);
      }
    }
    __syncthreads();  // S1: releases poll; orders h2 double-buffer turnover

    // s==0 row fetches prev group's bottom-row h2 from the coherence point
    if (s == 0 && g > 0 && act) {
      prevs[j] = __hip_atomic_load(h2buf + pbase + (size_t)t * HH,
                                   __ATOMIC_RELAXED, __HIP_MEMORY_SCOPE_AGENT);
    }

    if (act) {
      const float* hb2 = h2rd + s * HH;  // own h2 at t-1
      // gh dots for all 3 layers use last step's h (hides pv latency)
      float ghr0 = bias[j]          + dot32(Whh0 + j * WSTR, hb0);
      float ghz0 = bias[32 + j]     + dot32(Whh0 + (32 + j) * WSTR, hb0);
      float ghn0 = bias[64 + j]     + dot32(Whh0 + (64 + j) * WSTR, hb0);
      float ghr1 = bias[2*GG + j]      + dot32(Whh1 + j * WSTR, hb1);
      float ghz1 = bias[2*GG + 32 + j] + dot32(Whh1 + (32 + j) * WSTR, hb1);
      float ghn1 = bias[2*GG + 64 + j] + dot32(Whh1 + (64 + j) * WSTR, hb1);
      float ghr2 = bias[4*GG + j]      + dot32(Whh2 + j * WSTR, hb2);
      float ghz2 = bias[4*GG + 32 + j] + dot32(Whh2 + (32 + j) * WSTR, hb2);
      float ghn2 = bias[4*GG + 64 + j] + dot32(Whh2 + (64 + j) * WSTR, hb2);

      // layer 0: gi = P[v] + rp + Wf@prev   (prev row h2 at same t)
      const float* pb = (s == 0) ? prevs : (h2rd + (s - 1) * HH);
      {
        float gir = Pr + rpr + dot32(Wf + j * WSTR, pb);
        float giz = Pz + rpz + dot32(Wf + (32 + j) * WSTR, pb);
        float gin = Pn + rpn + dot32(Wf + (64 + j) * WSTR, pb);
        float rg = sigm(gir + ghr0);
        float zg = sigm(giz + ghz0);
        float ng = tanhfast(gin + rg * ghn0);
        h0r = (1.f - zg) * ng + zg * h0r;
      }
      h0s[s * HH + j] = h0r;   // consumed by own half-wave only (in-wave order)

      // layer 1
      {
        float gir = bias[GG + j]        + dot32(Wih1 + j * WSTR, hb0);
        float giz = bias[GG + 32 + j]   + dot32(Wih1 + (32 + j) * WSTR, hb0);
        float gin = bias[GG + 64 + j]   + dot32(Wih1 + (64 + j) * WSTR, hb0);
        float rg = sigm(gir + ghr1);
        float zg = sigm(giz + ghz1);
        float ng = tanhfast(gin + rg * ghn1);
        h1r = (1.f - zg) * ng + zg * h1r;
      }
      h1s[s * HH + j] = h1r;

      // layer 2
      {
        float gir = bias[3*GG + j]        + dot32(Wih2 + j * WSTR, hb1);
        float giz = bias[3*GG + 32 + j]   + dot32(Wih2 + (32 + j) * WSTR, hb1);
        float gin = bias[3*GG + 64 + j]   + dot32(Wih2 + (64 + j) * WSTR, hb1);
        float rg = sigm(gir + ghr2);
        float zg = sigm(giz + ghz2);
        float ng = tanhfast(gin + rg * ghn2);
        h2r = (1.f - zg) * ng + zg * h2r;
      }
      h2w[s * HH + j] = h2r;   // next iter's reader (row s+1 / own gh2) is behind S1

      if (s == RPB - 1) {
        // bottom row: write-through to coherence point for the next group
        __hip_atomic_store(h2buf + obase + (size_t)t * HH, h2r,
                           __ATOMIC_RELAXED, __HIP_MEMORY_SCOPE_AGENT);
      } else {
        // interior rows: only proj_kernel reads these (kernel-boundary ordering)
        h2buf[obase + (size_t)t * HH] = h2r;
      }
    }

    // publish: wave 3 (owns row 7) drains ITS OWN vmem (covers the s==7 agent
    // stores above, program-ordered in the same wave) and publishes. No
    // barrier needed; consumer only depends on the bottom row's data.
    if (tid == 224 && i >= RPB - 1) {
      asm volatile("s_waitcnt vmcnt(0)" ::: "memory");
      __hip_atomic_store(myflag, i - (RPB - 2), __ATOMIC_RELAXED, __HIP_MEMORY_SCOPE_AGENT);
    }

    vcur = vnext;
  }
}

// ------------------------------------------------------------------
// projection: pred[pos][v] = b_out[v] + w_out[v] . h2[pos]
// 8192 blocks x 32 positions; stage in LDS for coalesced writes
// ------------------------------------------------------------------
__global__ __launch_bounds__(256)
void proj_kernel(const float* __restrict__ h2buf, const float* __restrict__ wout,
                 const float* __restrict__ bout, float* __restrict__ out) {
  __shared__ float stage[32 * 258];
  const int tid = threadIdx.x;
  const int p = tid & 31, vq = tid >> 5;   // 8 vq groups
  const size_t pos = (size_t)blockIdx.x * 32 + p;
  const float* hrow = h2buf + pos * HH;
  float h[HH];
#pragma unroll
  for (int k = 0; k < HH; k += 4) {
    float4 f = *(const float4*)(hrow + k);
    h[k] = f.x; h[k + 1] = f.y; h[k + 2] = f.z; h[k + 3] = f.w;
  }
#pragma unroll 1
  for (int vi = 0; vi <= 32; ++vi) {
    int v = vq + vi * 8;
    if (v < 258) {
      const float* wrow = wout + v * HH;   // wave-uniform per vq group -> broadcast, L1-resident
      float a0 = bout[v], a1 = 0.f;
#pragma unroll
      for (int k = 0; k < HH; k += 4) {
        float4 w = *(const float4*)(wrow + k);
        a0 = fmaf(w.x, h[k],     fmaf(w.y, h[k + 1], a0));
        a1 = fmaf(w.z, h[k + 2], fmaf(w.w, h[k + 3], a1));
      }
      stage[p * 258 + v] = a0 + a1;
    }
  }
  __syncthreads();
  float* o = out + (size_t)blockIdx.x * 32 * 258;
#pragma unroll 1
  for (int i = tid; i < 32 * 258; i += 256) o[i] = stage[i];
}

// ------------------------------------------------------------------
extern "C" void kernel_launch(void* const* d_in, const int* in_sizes, int n_in,
                              void* d_out, int out_size, void* d_ws, size_t ws_size,
                              hipStream_t stream) {
  const int*   x    = (const int*)d_in[0];
  const float* emb  = (const float*)d_in[1];
  const float* wih0 = (const float*)d_in[2];
  const float* whh0 = (const float*)d_in[3];
  const float* bih0 = (const float*)d_in[4];
  const float* bhh0 = (const float*)d_in[5];
  const float* wih1 = (const float*)d_in[6];
  const float* whh1 = (const float*)d_in[7];
  const float* bih1 = (const float*)d_in[8];
  const float* bhh1 = (const float*)d_in[9];
  const float* wih2 = (const float*)d_in[10];
  const float* whh2 = (const float*)d_in[11];
  const float* bih2 = (const float*)d_in[12];
  const float* bhh2 = (const float*)d_in[13];
  const float* wh2e = (const float*)d_in[14];
  const float* bh2e = (const float*)d_in[15];
  const float* wout = (const float*)d_in[16];
  const float* bout = (const float*)d_in[17];
  float* out = (float*)d_out;

  char*  ws    = (char*)d_ws;
  float* h2buf = (float*)ws;
  int*   flags = (int*)(ws + FLAG_OFF);
  float* Ptab  = (float*)(ws + PTAB_OFF);
  float* Wf    = (float*)(ws + WF_OFF);

  hipMemsetAsync(flags, 0, FLAG_BYTES, stream);
  prep_kernel<<<354, 128, 0, stream>>>(emb, wih0, bih0, wh2e, bh2e, Ptab, Wf);

  const int rnn_lds_bytes = (6 * GG * WSTR + 5 * GG + HH + 4 * RPB * HH) * 4;  // 84,480 B
  hipFuncSetAttribute((const void*)rnn_kernel,
                      hipFuncAttributeMaxDynamicSharedMemorySize, rnn_lds_bytes);
  rnn_kernel<<<NRG * BATCH, 256, rnn_lds_bytes, stream>>>(
      x, wih0, whh0, bhh0, wih1, whh1, bih1, bhh1, wih2, whh2, bih2, bhh2,
      Ptab, Wf, h2buf, flags);

  proj_kernel<<<8192, 256, 0, stream>>>(h2buf, wout, bout, out);
}

// Round 3
// 1677.693 us; speedup vs baseline: 1.0909x; 1.0909x over previous
//
#include <hip/hip_runtime.h>
#include <math.h>

// ---------------- problem constants ----------------
#define BATCH 16
#define RWS   128     // rows
#define TT    128     // time steps per row (cols*C)
#define HH    32      // hidden
#define GG    96      // 3*H gate rows
#define RPB   8       // rows per block (diagonal pipeline inside block)
#define NRG   (RWS/RPB) // 16 row groups -> chain of 16 blocks, 15 flag hops
#define WP    100     // packed weight row stride (floats): [r|z|n] 96 + 4 pad, 16B aligned
#define FSTR  16      // flag stride in ints (64 B)

// ---------------- workspace layout (bytes) ----------------
#define H2_BYTES   (BATCH*RWS*TT*HH*4)          // 33,554,432
#define FLAG_OFF   H2_BYTES
#define FLAG_BYTES (NRG*BATCH*FSTR*4)           // 16,384
#define PTAB_OFF   (FLAG_OFF + FLAG_BYTES)
#define WF_OFF     (PTAB_OFF + 258*GG*4)        // Ptab: 258*96 fp32

__device__ __forceinline__ float sigm(float x) { return 1.0f / (1.0f + __expf(-x)); }
__device__ __forceinline__ float tanhfast(float x) {
  x = fminf(fmaxf(x, -15.0f), 15.0f);
  float e = __expf(2.0f * x);
  return (e - 1.0f) / (e + 1.0f);
}

// raw barrier: LDS visibility only, NO vmcnt drain (global stores free-run)
__device__ __forceinline__ void barrier_lgkm() {
  __builtin_amdgcn_sched_barrier(0);
  asm volatile("s_waitcnt lgkmcnt(0)" ::: "memory");
  __builtin_amdgcn_s_barrier();
  __builtin_amdgcn_sched_barrier(0);
}

// 32-dot: w from packed LDS row (float4 x8, 16B aligned), v in registers
__device__ __forceinline__ float dot32p(const float4* __restrict__ w, const float4 v[8]) {
  float a0 = 0.f, a1 = 0.f, a2 = 0.f, a3 = 0.f;
#pragma unroll
  for (int c = 0; c < 8; ++c) {
    float4 W = w[c];
    a0 = fmaf(W.x, v[c].x, a0);
    a1 = fmaf(W.y, v[c].y, a1);
    a2 = fmaf(W.z, v[c].z, a2);
    a3 = fmaf(W.w, v[c].w, a3);
  }
  return (a0 + a1) + (a2 + a3);
}

__device__ __forceinline__ void hoist8(float4 dst[8], const float* __restrict__ src) {
  const float4* p = (const float4*)src;
#pragma unroll
  for (int c = 0; c < 8; ++c) dst[c] = p[c];
}

// ------------------------------------------------------------------
// prep: P[v][g] = b_ih0[g] + sum_k<64 Wih0[g][k] emb[v][k] + sum_k<65 Wih0[g][k] b_h2e[k]
//       Wf[g][j] = sum_k<65 Wih0[g][k] Wh2e[k][j]
// ------------------------------------------------------------------
__global__ __launch_bounds__(128)
void prep_kernel(const float* __restrict__ emb, const float* __restrict__ wih0,
                 const float* __restrict__ bih0, const float* __restrict__ wh2e,
                 const float* __restrict__ bh2e, float* __restrict__ Ptab,
                 float* __restrict__ Wfo) {
  const int blk = blockIdx.x, tid = threadIdx.x;
  if (blk < 258) {
    if (tid < GG) {
      const float* wr = wih0 + tid * 65;
      const float* e  = emb + blk * 64;
      float acc = bih0[tid];
      for (int k = 0; k < 64; ++k) acc = fmaf(wr[k], e[k], acc);
      for (int k = 0; k < 65; ++k) acc = fmaf(wr[k], bh2e[k], acc);
      Ptab[blk * GG + tid] = acc;
    }
  } else {
    const int g = blk - 258;
    if (tid < HH) {
      const float* wr = wih0 + g * 65;
      float acc = 0.f;
      for (int k = 0; k < 65; ++k) acc = fmaf(wr[k], wh2e[k * HH + tid], acc);
      Wfo[g * HH + tid] = acc;
    }
  }
}

// ------------------------------------------------------------------
// load a [96x32] row-major global matrix into packed-gate LDS layout:
// dst[j*WP + gate*32 + k] = src[(gate*32 + j)*32 + k]
// ------------------------------------------------------------------
__device__ __forceinline__ void loadmat_packed(const float* __restrict__ src,
                                               float* __restrict__ dst, int tid) {
  for (int i = tid; i < GG * HH; i += 256) {
    const int g = i >> 5, k = i & 31;
    const int gate = g >> 5, j = g & 31;
    dst[j * WP + gate * 32 + k] = src[g * 32 + k];
  }
}

// ------------------------------------------------------------------
// RNN wavefront kernel v3: 8 rows/block diagonal, packed-b128 weights,
// register-hoisted h vectors, raw lgkm-only barrier, prefetched pv + cached
// flag polling. 256 blocks = (group, batch); 256 thr = (row s, j).
// ------------------------------------------------------------------
__global__ __launch_bounds__(256, 1)
void rnn_kernel(const int* __restrict__ xg, const float* __restrict__ wih0,
                const float* __restrict__ whh0g, const float* __restrict__ bhh0g,
                const float* __restrict__ wih1g, const float* __restrict__ whh1g,
                const float* __restrict__ bih1g, const float* __restrict__ bhh1g,
                const float* __restrict__ wih2g, const float* __restrict__ whh2g,
                const float* __restrict__ bih2g, const float* __restrict__ bhh2g,
                const float* __restrict__ Ptab, const float* __restrict__ Wfg,
                float* __restrict__ h2buf, int* __restrict__ flags) {
  extern __shared__ __align__(16) float lds[];
  float* Wf    = lds;                  // 32*WP
  float* Whh0  = Wf   + HH * WP;
  float* Wih1  = Whh0 + HH * WP;
  float* Whh1  = Wih1 + HH * WP;
  float* Wih2  = Whh1 + HH * WP;
  float* Whh2  = Wih2 + HH * WP;
  float* prevs = Whh2 + HH * WP;       // 32: pv staging for s==0 row
  float* h0s   = prevs + HH;           // 8*32
  float* h1s   = h0s + RPB * HH;       // 8*32
  float* h2a   = h1s + RPB * HH;       // 8*32 double buffer A
  float* h2b   = h2a + RPB * HH;       // 8*32 double buffer B

  const int tid = threadIdx.x;
  const int j   = tid & 31;
  const int s   = tid >> 5;           // row within group
  const int g   = blockIdx.x >> 4;    // row group (chain position)
  const int bat = blockIdx.x & 15;    // batch
  const int row = g * RPB + s;

  loadmat_packed(Wfg,   Wf,   tid);
  loadmat_packed(whh0g, Whh0, tid);
  loadmat_packed(wih1g, Wih1, tid);
  loadmat_packed(whh1g, Whh1, tid);
  loadmat_packed(wih2g, Wih2, tid);
  loadmat_packed(whh2g, Whh2, tid);
  h0s[tid] = 0.f; h1s[tid] = 0.f; h2a[tid] = 0.f; h2b[tid] = 0.f;
  if (tid < HH) prevs[tid] = 0.f;

  // per-lane constants: biases (shared across rows) + row-position terms
  const float bh0r = bhh0g[j], bh0z = bhh0g[32 + j], bh0n = bhh0g[64 + j];
  const float bi1r = bih1g[j], bi1z = bih1g[32 + j], bi1n = bih1g[64 + j];
  const float bh1r = bhh1g[j], bh1z = bhh1g[32 + j], bh1n = bhh1g[64 + j];
  const float bi2r = bih2g[j], bi2z = bih2g[32 + j], bi2n = bih2g[64 + j];
  const float bh2r_ = bhh2g[j], bh2z_ = bhh2g[32 + j], bh2n_ = bhh2g[64 + j];
  const float rowpos = (float)row * (2.0f / 128.0f) - 1.0f;
  const float rpr = wih0[j * 65 + 64] * rowpos;
  const float rpz = wih0[(32 + j) * 65 + 64] * rowpos;
  const float rpn = wih0[(64 + j) * 65 + 64] * rowpos;
  __syncthreads();

  float h0r = 0.f, h1r = 0.f, h2r = 0.f;
  float4 Vh0[8], Vh1[8], Vh2[8], Vp[8];
#pragma unroll
  for (int c = 0; c < 8; ++c) {
    Vh0[c] = make_float4(0.f, 0.f, 0.f, 0.f);
    Vh1[c] = make_float4(0.f, 0.f, 0.f, 0.f);
    Vh2[c] = make_float4(0.f, 0.f, 0.f, 0.f);
  }

  const size_t xbase = (size_t)(bat * RWS + row) * TT;
  const size_t obase = (size_t)(bat * RWS + row) * TT * HH + j;
  const size_t pbase = (row > 0) ? ((size_t)(bat * RWS + (row - 1)) * TT * HH + j) : 0;
  int* myflag = flags + (g * BATCH + bat) * FSTR;
  const int* pflag = flags + ((g > 0 ? g - 1 : 0) * BATCH + bat) * FSTR;

  int vcur = xg[xbase];
  float pvq = 0.f;
  int lastF = 0;

  // prologue: g>0 needs pv(t=0) preloaded before iteration 0
  if (g > 0) {
    if (tid == 0) {
      int f;
      do { f = __hip_atomic_load(pflag, __ATOMIC_RELAXED, __HIP_MEMORY_SCOPE_AGENT); }
      while (f < 1);
      lastF = f;
    }
    __syncthreads();
    if (s == 0)
      pvq = __hip_atomic_load(h2buf + pbase, __ATOMIC_RELAXED, __HIP_MEMORY_SCOPE_AGENT);
  }

  for (int i = 0; i < TT + RPB - 1; ++i) {
    const int t = i - s;                       // own time step
    const bool act = (t >= 0) && (t < TT);
    const float* h2rd = (i & 1) ? h2a : h2b;   // written at iter i-1
    float*       h2w  = (i & 1) ? h2b : h2a;   // written this iter

    // publish at iteration TOP: wave3's stores from iter i-1 are long complete,
    // so the vmcnt(0) drain is ~free. Value = bottom-row completed t count.
    if (tid == 224 && i >= RPB) {
      asm volatile("s_waitcnt vmcnt(0)" ::: "memory");
      __hip_atomic_store(myflag, i - (RPB - 1), __ATOMIC_RELAXED, __HIP_MEMORY_SCOPE_AGENT);
    }

    // prefetch next token + P-table rows (global, free-running across barrier)
    const int tn = t + 1;
    const int vnext = (tn >= 0 && tn < TT) ? xg[xbase + tn] : 0;
    const float Pr = Ptab[vcur * GG + j];
    const float Pz = Ptab[vcur * GG + 32 + j];
    const float Pn = Ptab[vcur * GG + 64 + j];

    // chain handoff: ensure producer finished t=i+1 (for this iter's pv prefetch).
    // Cached flag: in steady state producer is ~9 ahead -> poll ~1-in-8 iters.
    if (g > 0 && i < TT - 1) {
      if (tid == 0 && lastF < i + 2) {
        int f;
        do { f = __hip_atomic_load(pflag, __ATOMIC_RELAXED, __HIP_MEMORY_SCOPE_AGENT); }
        while (f < i + 2);
        lastF = f;
      }
    }
    barrier_lgkm();  // S1: releases poll; orders h2 double-buffer turnover

    // s==0: stage current pv (preloaded last iter), prefetch next pv
    if (s == 0 && g > 0) {
      if (act) prevs[j] = pvq;
      if (i + 1 < TT)
        pvq = __hip_atomic_load(h2buf + pbase + (size_t)(i + 1) * HH,
                                __ATOMIC_RELAXED, __HIP_MEMORY_SCOPE_AGENT);
    }

    if (act) {
      // gh dots from carried old h vectors (registers)
      const float ghr0 = bh0r + dot32p((const float4*)(Whh0 + j * WP),      Vh0);
      const float ghz0 = bh0z + dot32p((const float4*)(Whh0 + j * WP + 32), Vh0);
      const float ghn0 = bh0n + dot32p((const float4*)(Whh0 + j * WP + 64), Vh0);
      const float ghr1 = bh1r + dot32p((const float4*)(Whh1 + j * WP),      Vh1);
      const float ghz1 = bh1z + dot32p((const float4*)(Whh1 + j * WP + 32), Vh1);
      const float ghn1 = bh1n + dot32p((const float4*)(Whh1 + j * WP + 64), Vh1);
      const float ghr2 = bh2r_ + dot32p((const float4*)(Whh2 + j * WP),      Vh2);
      const float ghz2 = bh2z_ + dot32p((const float4*)(Whh2 + j * WP + 32), Vh2);
      const float ghn2 = bh2n_ + dot32p((const float4*)(Whh2 + j * WP + 64), Vh2);

      // layer 0: gi = P[v] + rp + Wf @ prev-row h2 (same t)
      hoist8(Vp, (s == 0) ? prevs : (h2rd + (s - 1) * HH));
      {
        const float gir = Pr + rpr + dot32p((const float4*)(Wf + j * WP),      Vp);
        const float giz = Pz + rpz + dot32p((const float4*)(Wf + j * WP + 32), Vp);
        const float gin = Pn + rpn + dot32p((const float4*)(Wf + j * WP + 64), Vp);
        const float rg = sigm(gir + ghr0);
        const float zg = sigm(giz + ghz0);
        const float ng = tanhfast(gin + rg * ghn0);
        h0r = (1.f - zg) * ng + zg * h0r;
      }
      h0s[s * HH + j] = h0r;          // own half-wave only; in-wave LDS order
      hoist8(Vh0, h0s + s * HH);      // h0_new vector (also next iter's old)

      // layer 1
      {
        const float gir = bi1r + dot32p((const float4*)(Wih1 + j * WP),      Vh0);
        const float giz = bi1z + dot32p((const float4*)(Wih1 + j * WP + 32), Vh0);
        const float gin = bi1n + dot32p((const float4*)(Wih1 + j * WP + 64), Vh0);
        const float rg = sigm(gir + ghr1);
        const float zg = sigm(giz + ghz1);
        const float ng = tanhfast(gin + rg * ghn1);
        h1r = (1.f - zg) * ng + zg * h1r;
      }
      h1s[s * HH + j] = h1r;
      hoist8(Vh1, h1s + s * HH);

      // layer 2
      {
        const float gir = bi2r + dot32p((const float4*)(Wih2 + j * WP),      Vh1);
        const float giz = bi2z + dot32p((const float4*)(Wih2 + j * WP + 32), Vh1);
        const float gin = bi2n + dot32p((const float4*)(Wih2 + j * WP + 64), Vh1);
        const float rg = sigm(gir + ghr2);
        const float zg = sigm(giz + ghz2);
        const float ng = tanhfast(gin + rg * ghn2);
        h2r = (1.f - zg) * ng + zg * h2r;
      }
      h2w[s * HH + j] = h2r;          // neighbor reads next iter (behind barrier)
      hoist8(Vh2, h2w + s * HH);      // own h2_new -> next iter's old

      if (s == RPB - 1) {
        // bottom row: write-through to coherence point for the next group
        __hip_atomic_store(h2buf + obase + (size_t)t * HH, h2r,
                           __ATOMIC_RELAXED, __HIP_MEMORY_SCOPE_AGENT);
      } else {
        // interior rows: only proj_kernel reads these (kernel-boundary ordering)
        h2buf[obase + (size_t)t * HH] = h2r;
      }
    }

    vcur = vnext;
  }

  // final publish: bottom row completed all TT steps
  if (tid == 224) {
    asm volatile("s_waitcnt vmcnt(0)" ::: "memory");
    __hip_atomic_store(myflag, TT, __ATOMIC_RELAXED, __HIP_MEMORY_SCOPE_AGENT);
  }
}

// ------------------------------------------------------------------
// projection: pred[pos][v] = b_out[v] + w_out[v] . h2[pos]
// 8192 blocks x 32 positions; stage in LDS for coalesced writes
// ------------------------------------------------------------------
__global__ __launch_bounds__(256)
void proj_kernel(const float* __restrict__ h2buf, const float* __restrict__ wout,
                 const float* __restrict__ bout, float* __restrict__ out) {
  __shared__ float stage[32 * 258];
  const int tid = threadIdx.x;
  const int p = tid & 31, vq = tid >> 5;   // 8 vq groups
  const size_t pos = (size_t)blockIdx.x * 32 + p;
  const float* hrow = h2buf + pos * HH;
  float h[HH];
#pragma unroll
  for (int k = 0; k < HH; k += 4) {
    float4 f = *(const float4*)(hrow + k);
    h[k] = f.x; h[k + 1] = f.y; h[k + 2] = f.z; h[k + 3] = f.w;
  }
#pragma unroll 1
  for (int vi = 0; vi <= 32; ++vi) {
    int v = vq + vi * 8;
    if (v < 258) {
      const float* wrow = wout + v * HH;   // wave-uniform per vq group -> broadcast
      float a0 = bout[v], a1 = 0.f;
#pragma unroll
      for (int k = 0; k < HH; k += 4) {
        float4 w = *(const float4*)(wrow + k);
        a0 = fmaf(w.x, h[k],     fmaf(w.y, h[k + 1], a0));
        a1 = fmaf(w.z, h[k + 2], fmaf(w.w, h[k + 3], a1));
      }
      stage[p * 258 + v] = a0 + a1;
    }
  }
  __syncthreads();
  float* o = out + (size_t)blockIdx.x * 32 * 258;
#pragma unroll 1
  for (int i = tid; i < 32 * 258; i += 256) o[i] = stage[i];
}

// ------------------------------------------------------------------
extern "C" void kernel_launch(void* const* d_in, const int* in_sizes, int n_in,
                              void* d_out, int out_size, void* d_ws, size_t ws_size,
                              hipStream_t stream) {
  const int*   x    = (const int*)d_in[0];
  const float* emb  = (const float*)d_in[1];
  const float* wih0 = (const float*)d_in[2];
  const float* whh0 = (const float*)d_in[3];
  const float* bih0 = (const float*)d_in[4];
  const float* bhh0 = (const float*)d_in[5];
  const float* wih1 = (const float*)d_in[6];
  const float* whh1 = (const float*)d_in[7];
  const float* bih1 = (const float*)d_in[8];
  const float* bhh1 = (const float*)d_in[9];
  const float* wih2 = (const float*)d_in[10];
  const float* whh2 = (const float*)d_in[11];
  const float* bih2 = (const float*)d_in[12];
  const float* bhh2 = (const float*)d_in[13];
  const float* wh2e = (const float*)d_in[14];
  const float* bh2e = (const float*)d_in[15];
  const float* wout = (const float*)d_in[16];
  const float* bout = (const float*)d_in[17];
  float* out = (float*)d_out;

  char*  ws    = (char*)d_ws;
  float* h2buf = (float*)ws;
  int*   flags = (int*)(ws + FLAG_OFF);
  float* Ptab  = (float*)(ws + PTAB_OFF);
  float* Wf    = (float*)(ws + WF_OFF);

  hipMemsetAsync(flags, 0, FLAG_BYTES, stream);
  prep_kernel<<<354, 128, 0, stream>>>(emb, wih0, bih0, wh2e, bh2e, Ptab, Wf);

  const int rnn_lds_bytes = (6 * HH * WP + HH + 4 * RPB * HH) * 4;  // 81,024 B
  hipFuncSetAttribute((const void*)rnn_kernel,
                      hipFuncAttributeMaxDynamicSharedMemorySize, rnn_lds_bytes);
  rnn_kernel<<<NRG * BATCH, 256, rnn_lds_bytes, stream>>>(
      x, wih0, whh0, bhh0, wih1, whh1, bih1, bhh1, wih2, whh2, bih2, bhh2,
      Ptab, Wf, h2buf, flags);

  proj_kernel<<<8192, 256, 0, stream>>>(h2buf, wout, bout, out);
}

// Round 5
// 1624.366 us; speedup vs baseline: 1.1267x; 1.0328x over previous
//
#include <hip/hip_runtime.h>
#include <math.h>

// ---------------- problem constants ----------------
#define BATCH 16
#define RWS   128     // rows
#define TT    128     // time steps per row (cols*C)
#define HH    32      // hidden
#define GG    96      // 3*H gate rows
#define RPB   8       // rows per block (diagonal pipeline inside block)
#define NRG   (RWS/RPB) // 16 row groups -> chain of 16 blocks, 15 flag hops
#define WP    100     // packed weight row stride (floats): [r|z|n] 96 + 4 pad, 16B aligned
#define FSTR  16      // flag stride in ints (64 B)

// ---------------- workspace layout (bytes) ----------------
#define H2_BYTES   (BATCH*RWS*TT*HH*4)          // 33,554,432
#define FLAG_OFF   H2_BYTES
#define FLAG_BYTES (NRG*BATCH*FSTR*4)           // 16,384
#define PTAB_OFF   (FLAG_OFF + FLAG_BYTES)
#define WF_OFF     (PTAB_OFF + 258*GG*4)        // Ptab: 258*96 fp32

__device__ __forceinline__ float sigm(float x) { return 1.0f / (1.0f + __expf(-x)); }
__device__ __forceinline__ float tanhfast(float x) {
  x = fminf(fmaxf(x, -15.0f), 15.0f);
  float e = __expf(2.0f * x);
  return (e - 1.0f) / (e + 1.0f);
}

// raw barrier: LDS visibility only, NO vmcnt drain (global stores free-run)
__device__ __forceinline__ void barrier_lgkm() {
  __builtin_amdgcn_sched_barrier(0);
  asm volatile("s_waitcnt lgkmcnt(0)" ::: "memory");
  __builtin_amdgcn_s_barrier();
  __builtin_amdgcn_sched_barrier(0);
}

// 32-dot: w from packed LDS row (float4 x8, 16B aligned), v in registers
__device__ __forceinline__ float dot32p(const float4* __restrict__ w, const float4 v[8]) {
  float a0 = 0.f, a1 = 0.f, a2 = 0.f, a3 = 0.f;
#pragma unroll
  for (int c = 0; c < 8; ++c) {
    float4 W = w[c];
    a0 = fmaf(W.x, v[c].x, a0);
    a1 = fmaf(W.y, v[c].y, a1);
    a2 = fmaf(W.z, v[c].z, a2);
    a3 = fmaf(W.w, v[c].w, a3);
  }
  return (a0 + a1) + (a2 + a3);
}

// 32-dot: both operands in registers (pure VALU, no memory dependency)
__device__ __forceinline__ float dotrr(const float4 w[8], const float4 v[8]) {
  float a0 = 0.f, a1 = 0.f, a2 = 0.f, a3 = 0.f;
#pragma unroll
  for (int c = 0; c < 8; ++c) {
    a0 = fmaf(w[c].x, v[c].x, a0);
    a1 = fmaf(w[c].y, v[c].y, a1);
    a2 = fmaf(w[c].z, v[c].z, a2);
    a3 = fmaf(w[c].w, v[c].w, a3);
  }
  return (a0 + a1) + (a2 + a3);
}

__device__ __forceinline__ void hoist8(float4 dst[8], const float* __restrict__ src) {
  const float4* p = (const float4*)src;
#pragma unroll
  for (int c = 0; c < 8; ++c) dst[c] = p[c];
}

// ------------------------------------------------------------------
// prep: P[v][g] = b_ih0[g] + sum_k<64 Wih0[g][k] emb[v][k] + sum_k<65 Wih0[g][k] b_h2e[k]
//       Wf[g][j] = sum_k<65 Wih0[g][k] Wh2e[k][j]
// ------------------------------------------------------------------
__global__ __launch_bounds__(128)
void prep_kernel(const float* __restrict__ emb, const float* __restrict__ wih0,
                 const float* __restrict__ bih0, const float* __restrict__ wh2e,
                 const float* __restrict__ bh2e, float* __restrict__ Ptab,
                 float* __restrict__ Wfo) {
  const int blk = blockIdx.x, tid = threadIdx.x;
  if (blk < 258) {
    if (tid < GG) {
      const float* wr = wih0 + tid * 65;
      const float* e  = emb + blk * 64;
      float acc = bih0[tid];
      for (int k = 0; k < 64; ++k) acc = fmaf(wr[k], e[k], acc);
      for (int k = 0; k < 65; ++k) acc = fmaf(wr[k], bh2e[k], acc);
      Ptab[blk * GG + tid] = acc;
    }
  } else {
    const int g = blk - 258;
    if (tid < HH) {
      const float* wr = wih0 + g * 65;
      float acc = 0.f;
      for (int k = 0; k < 65; ++k) acc = fmaf(wr[k], wh2e[k * HH + tid], acc);
      Wfo[g * HH + tid] = acc;
    }
  }
}

// ------------------------------------------------------------------
// load a [96x32] row-major global matrix into packed-gate LDS layout:
// dst[j*WP + gate*32 + k] = src[(gate*32 + j)*32 + k]
// ------------------------------------------------------------------
__device__ __forceinline__ void loadmat_packed(const float* __restrict__ src,
                                               float* __restrict__ dst, int tid) {
  for (int i = tid; i < GG * HH; i += 256) {
    const int g = i >> 5, k = i & 31;
    const int gate = g >> 5, j = g & 31;
    dst[j * WP + gate * 32 + k] = src[g * 32 + k];
  }
}

// ------------------------------------------------------------------
// RNN wavefront kernel v4b: 8 rows/block diagonal, cross-barrier pipelined gh.
//  - Whh0 & Whh2 gate rows live in per-lane VGPRs (192 regs): their gh dots
//    are pure VALU. Whh1 stays in LDS (register-pressure headroom).
//  - gh dots for step t+1 are computed DURING step t (right after each h is
//    produced) -> pre-barrier stall-filler; post-barrier critical path is
//    only the 3 LDS gi-dots + activations per layer.
// 256 blocks = (group, batch); 256 thr = (row s, j); 1 wave/SIMD.
// ------------------------------------------------------------------
__global__ __launch_bounds__(256, 1)
void rnn_kernel(const int* __restrict__ xg, const float* __restrict__ wih0,
                const float* __restrict__ whh0g, const float* __restrict__ bhh0g,
                const float* __restrict__ wih1g, const float* __restrict__ whh1g,
                const float* __restrict__ bih1g, const float* __restrict__ bhh1g,
                const float* __restrict__ wih2g, const float* __restrict__ whh2g,
                const float* __restrict__ bih2g, const float* __restrict__ bhh2g,
                const float* __restrict__ Ptab, const float* __restrict__ Wfg,
                float* __restrict__ h2buf, int* __restrict__ flags) {
  extern __shared__ __align__(16) float lds[];
  float* Wf    = lds;                  // 32*WP
  float* Wih1  = Wf   + HH * WP;
  float* Whh1  = Wih1 + HH * WP;
  float* Wih2  = Whh1 + HH * WP;
  float* prevs = Wih2 + HH * WP;       // 32: pv staging for s==0 row
  float* h0s   = prevs + HH;           // 8*32
  float* h1s   = h0s + RPB * HH;       // 8*32
  float* h2a   = h1s + RPB * HH;       // 8*32 double buffer A
  float* h2b   = h2a + RPB * HH;       // 8*32 double buffer B

  const int tid = threadIdx.x;
  const int j   = tid & 31;
  const int s   = tid >> 5;           // row within group
  const int g   = blockIdx.x >> 4;    // row group (chain position)
  const int bat = blockIdx.x & 15;    // batch
  const int row = g * RPB + s;

  loadmat_packed(Wfg,   Wf,   tid);
  loadmat_packed(wih1g, Wih1, tid);
  loadmat_packed(whh1g, Whh1, tid);
  loadmat_packed(wih2g, Wih2, tid);
  h0s[tid] = 0.f; h1s[tid] = 0.f; h2a[tid] = 0.f; h2b[tid] = 0.f;
  if (tid < HH) prevs[tid] = 0.f;

  // recurrent weights (layers 0,2) -> registers: lane j holds rows {j,32+j,64+j}
  float4 Wh0r[8], Wh0z[8], Wh0n[8], Wh2r[8], Wh2z[8], Wh2n[8];
  {
    const float4* W0 = (const float4*)whh0g;
    const float4* W2 = (const float4*)whh2g;
#pragma unroll
    for (int c = 0; c < 8; ++c) {
      Wh0r[c] = W0[j * 8 + c];
      Wh0z[c] = W0[(32 + j) * 8 + c];
      Wh0n[c] = W0[(64 + j) * 8 + c];
      Wh2r[c] = W2[j * 8 + c];
      Wh2z[c] = W2[(32 + j) * 8 + c];
      Wh2n[c] = W2[(64 + j) * 8 + c];
    }
  }

  // per-lane constants: biases + row-position terms
  const float bh0r = bhh0g[j], bh0z = bhh0g[32 + j], bh0n = bhh0g[64 + j];
  const float bi1r = bih1g[j], bi1z = bih1g[32 + j], bi1n = bih1g[64 + j];
  const float bh1r = bhh1g[j], bh1z = bhh1g[32 + j], bh1n = bhh1g[64 + j];
  const float bi2r = bih2g[j], bi2z = bih2g[32 + j], bi2n = bih2g[64 + j];
  const float bh2r_ = bhh2g[j], bh2z_ = bhh2g[32 + j], bh2n_ = bhh2g[64 + j];
  const float rowpos = (float)row * (2.0f / 128.0f) - 1.0f;
  const float rpr = wih0[j * 65 + 64] * rowpos;
  const float rpz = wih0[(32 + j) * 65 + 64] * rowpos;
  const float rpn = wih0[(64 + j) * 65 + 64] * rowpos;
  __syncthreads();

  float h0r = 0.f, h1r = 0.f, h2r = 0.f;
  // precomputed gh for the NEXT active step; h=0 initially -> gh = bias
  float ghr0p = bh0r, ghz0p = bh0z, ghn0p = bh0n;
  float ghr1p = bh1r, ghz1p = bh1z, ghn1p = bh1n;
  float ghr2p = bh2r_, ghz2p = bh2z_, ghn2p = bh2n_;

  const size_t xbase = (size_t)(bat * RWS + row) * TT;
  const size_t obase = (size_t)(bat * RWS + row) * TT * HH + j;
  const size_t pbase = (row > 0) ? ((size_t)(bat * RWS + (row - 1)) * TT * HH + j) : 0;
  int* myflag = flags + (g * BATCH + bat) * FSTR;
  const int* pflag = flags + ((g > 0 ? g - 1 : 0) * BATCH + bat) * FSTR;

  int vcur = xg[xbase];
  float pvq = 0.f;
  int lastF = 0;

  // prologue: g>0 needs pv(t=0) preloaded before iteration 0
  if (g > 0) {
    if (tid == 0) {
      int f;
      do { f = __hip_atomic_load(pflag, __ATOMIC_RELAXED, __HIP_MEMORY_SCOPE_AGENT); }
      while (f < 1 ? (__builtin_amdgcn_s_sleep(1), true) : false);
      lastF = f;
    }
    __syncthreads();
    if (s == 0)
      pvq = __hip_atomic_load(h2buf + pbase, __ATOMIC_RELAXED, __HIP_MEMORY_SCOPE_AGENT);
  }

  for (int i = 0; i < TT + RPB - 1; ++i) {
    const int t = i - s;                       // own time step
    const bool act = (t >= 0) && (t < TT);
    const float* h2rd = (i & 1) ? h2a : h2b;   // written at iter i-1
    float*       h2w  = (i & 1) ? h2b : h2a;   // written this iter

    // publish at iteration TOP: wave3's stores from iter i-1 are long complete,
    // so the vmcnt(0) drain is ~free. Value = bottom-row completed t count.
    if (tid == 224 && i >= RPB) {
      asm volatile("s_waitcnt vmcnt(0)" ::: "memory");
      __hip_atomic_store(myflag, i - (RPB - 1), __ATOMIC_RELAXED, __HIP_MEMORY_SCOPE_AGENT);
    }

    // prefetch next token + P-table rows (global, free-running across barrier)
    const int tn = t + 1;
    const int vnext = (tn >= 0 && tn < TT) ? xg[xbase + tn] : 0;
    const float Pr = Ptab[vcur * GG + j];
    const float Pz = Ptab[vcur * GG + 32 + j];
    const float Pn = Ptab[vcur * GG + 64 + j];

    // chain handoff: ensure producer finished t=i+1 (for this iter's pv prefetch).
    if (g > 0 && i < TT - 1) {
      if (tid == 0 && lastF < i + 2) {
        int f;
        do {
          f = __hip_atomic_load(pflag, __ATOMIC_RELAXED, __HIP_MEMORY_SCOPE_AGENT);
          if (f < i + 2) __builtin_amdgcn_s_sleep(1);
        } while (f < i + 2);
        lastF = f;
      }
    }
    barrier_lgkm();  // S1: releases poll; orders h2 double-buffer turnover

    // s==0: stage current pv (preloaded last iter), prefetch next pv
    if (s == 0 && g > 0) {
      if (act) prevs[j] = pvq;
      if (i + 1 < TT)
        pvq = __hip_atomic_load(h2buf + pbase + (size_t)(i + 1) * HH,
                                __ATOMIC_RELAXED, __HIP_MEMORY_SCOPE_AGENT);
    }

    if (act) {
      float4 Vt[8];

      // ---- layer 0: gi = P[v] + rp + Wf @ prev-row h2 (same t); gh precomputed
      hoist8(Vt, (s == 0) ? prevs : (h2rd + (s - 1) * HH));
      {
        const float gir = Pr + rpr + dot32p((const float4*)(Wf + j * WP),      Vt);
        const float giz = Pz + rpz + dot32p((const float4*)(Wf + j * WP + 32), Vt);
        const float gin = Pn + rpn + dot32p((const float4*)(Wf + j * WP + 64), Vt);
        const float rg = sigm(gir + ghr0p);
        const float zg = sigm(giz + ghz0p);
        const float ng = tanhfast(gin + rg * ghn0p);
        h0r = (1.f - zg) * ng + zg * h0r;
      }
      h0s[s * HH + j] = h0r;          // own half-wave only; in-wave LDS order
      hoist8(Vt, h0s + s * HH);       // h0_new (broadcast)

      // ---- layer 1 gi (LDS) + precompute gh0 for NEXT step (pure VALU)
      {
        const float gir = bi1r + dot32p((const float4*)(Wih1 + j * WP),      Vt);
        const float giz = bi1z + dot32p((const float4*)(Wih1 + j * WP + 32), Vt);
        const float gin = bi1n + dot32p((const float4*)(Wih1 + j * WP + 64), Vt);
        ghr0p = bh0r + dotrr(Wh0r, Vt);
        ghz0p = bh0z + dotrr(Wh0z, Vt);
        ghn0p = bh0n + dotrr(Wh0n, Vt);
        const float rg = sigm(gir + ghr1p);
        const float zg = sigm(giz + ghz1p);
        const float ng = tanhfast(gin + rg * ghn1p);
        h1r = (1.f - zg) * ng + zg * h1r;
      }
      h1s[s * HH + j] = h1r;
      hoist8(Vt, h1s + s * HH);       // h1_new (broadcast)

      // ---- layer 2 gi (LDS) + precompute gh1 for NEXT step (LDS-sourced, pre-barrier)
      {
        const float gir = bi2r + dot32p((const float4*)(Wih2 + j * WP),      Vt);
        const float giz = bi2z + dot32p((const float4*)(Wih2 + j * WP + 32), Vt);
        const float gin = bi2n + dot32p((const float4*)(Wih2 + j * WP + 64), Vt);
        ghr1p = bh1r + dot32p((const float4*)(Whh1 + j * WP),      Vt);
        ghz1p = bh1z + dot32p((const float4*)(Whh1 + j * WP + 32), Vt);
        ghn1p = bh1n + dot32p((const float4*)(Whh1 + j * WP + 64), Vt);
        const float rg = sigm(gir + ghr2p);
        const float zg = sigm(giz + ghz2p);
        const float ng = tanhfast(gin + rg * ghn2p);
        h2r = (1.f - zg) * ng + zg * h2r;
      }
      h2w[s * HH + j] = h2r;          // neighbor reads next iter (behind barrier)
      hoist8(Vt, h2w + s * HH);       // h2_new (broadcast)
      // precompute gh2 for NEXT step (pure VALU)
      ghr2p = bh2r_ + dotrr(Wh2r, Vt);
      ghz2p = bh2z_ + dotrr(Wh2z, Vt);
      ghn2p = bh2n_ + dotrr(Wh2n, Vt);

      if (s == RPB - 1) {
        // bottom row: write-through to coherence point for the next group
        __hip_atomic_store(h2buf + obase + (size_t)t * HH, h2r,
                           __ATOMIC_RELAXED, __HIP_MEMORY_SCOPE_AGENT);
      } else {
        // interior rows: only proj_kernel reads these (kernel-boundary ordering)
        h2buf[obase + (size_t)t * HH] = h2r;
      }
    }

    vcur = vnext;
  }

  // final publish: bottom row completed all TT steps
  if (tid == 224) {
    asm volatile("s_waitcnt vmcnt(0)" ::: "memory");
    __hip_atomic_store(myflag, TT, __ATOMIC_RELAXED, __HIP_MEMORY_SCOPE_AGENT);
  }
}

// ------------------------------------------------------------------
// projection: pred[pos][v] = b_out[v] + w_out[v] . h2[pos]
// 8192 blocks x 32 positions; stage in LDS for coalesced writes
// ------------------------------------------------------------------
__global__ __launch_bounds__(256)
void proj_kernel(const float* __restrict__ h2buf, const float* __restrict__ wout,
                 const float* __restrict__ bout, float* __restrict__ out) {
  __shared__ float stage[32 * 258];
  const int tid = threadIdx.x;
  const int p = tid & 31, vq = tid >> 5;   // 8 vq groups
  const size_t pos = (size_t)blockIdx.x * 32 + p;
  const float* hrow = h2buf + pos * HH;
  float h[HH];
#pragma unroll
  for (int k = 0; k < HH; k += 4) {
    float4 f = *(const float4*)(hrow + k);
    h[k] = f.x; h[k + 1] = f.y; h[k + 2] = f.z; h[k + 3] = f.w;
  }
#pragma unroll 1
  for (int vi = 0; vi <= 32; ++vi) {
    int v = vq + vi * 8;
    if (v < 258) {
      const float* wrow = wout + v * HH;   // wave-uniform per vq group -> broadcast
      float a0 = bout[v], a1 = 0.f;
#pragma unroll
      for (int k = 0; k < HH; k += 4) {
        float4 w = *(const float4*)(wrow + k);
        a0 = fmaf(w.x, h[k],     fmaf(w.y, h[k + 1], a0));
        a1 = fmaf(w.z, h[k + 2], fmaf(w.w, h[k + 3], a1));
      }
      stage[p * 258 + v] = a0 + a1;
    }
  }
  __syncthreads();
  float* o = out + (size_t)blockIdx.x * 32 * 258;
#pragma unroll 1
  for (int i = tid; i < 32 * 258; i += 256) o[i] = stage[i];
}

// ------------------------------------------------------------------
extern "C" void kernel_launch(void* const* d_in, const int* in_sizes, int n_in,
                              void* d_out, int out_size, void* d_ws, size_t ws_size,
                              hipStream_t stream) {
  const int*   x    = (const int*)d_in[0];
  const float* emb  = (const float*)d_in[1];
  const float* wih0 = (const float*)d_in[2];
  const float* whh0 = (const float*)d_in[3];
  const float* bih0 = (const float*)d_in[4];
  const float* bhh0 = (const float*)d_in[5];
  const float* wih1 = (const float*)d_in[6];
  const float* whh1 = (const float*)d_in[7];
  const float* bih1 = (const float*)d_in[8];
  const float* bhh1 = (const float*)d_in[9];
  const float* wih2 = (const float*)d_in[10];
  const float* whh2 = (const float*)d_in[11];
  const float* bih2 = (const float*)d_in[12];
  const float* bhh2 = (const float*)d_in[13];
  const float* wh2e = (const float*)d_in[14];
  const float* bh2e = (const float*)d_in[15];
  const float* wout = (const float*)d_in[16];
  const float* bout = (const float*)d_in[17];
  float* out = (float*)d_out;

  char*  ws    = (char*)d_ws;
  float* h2buf = (float*)ws;
  int*   flags = (int*)(ws + FLAG_OFF);
  float* Ptab  = (float*)(ws + PTAB_OFF);
  float* Wf    = (float*)(ws + WF_OFF);

  hipMemsetAsync(flags, 0, FLAG_BYTES, stream);
  prep_kernel<<<354, 128, 0, stream>>>(emb, wih0, bih0, wh2e, bh2e, Ptab, Wf);

  const int rnn_lds_bytes = (4 * HH * WP + HH + 4 * RPB * HH) * 4;  // 55,424 B
  hipFuncSetAttribute((const void*)rnn_kernel,
                      hipFuncAttributeMaxDynamicSharedMemorySize, rnn_lds_bytes);
  rnn_kernel<<<NRG * BATCH, 256, rnn_lds_bytes, stream>>>(
      x, wih0, whh0, bhh0, wih1, whh1, bih1, bhh1, wih2, whh2, bih2, bhh2,
      Ptab, Wf, h2buf, flags);

  proj_kernel<<<8192, 256, 0, stream>>>(h2buf, wout, bout, out);
}